// Round 1
// baseline (409.609 us; speedup 1.0000x reference)
//
#include <hip/hip_runtime.h>
#include <hip/hip_bf16.h>

#define L_SEQ 2048
#define DM 512
#define NH 8
#define DH 64
#define NB 4

typedef __attribute__((ext_vector_type(4))) float f32x4;
typedef __attribute__((ext_vector_type(8))) short bf16x8;
typedef __attribute__((ext_vector_type(4))) unsigned short u16x4;
typedef __attribute__((ext_vector_type(4))) int i32x4;
typedef unsigned long long u64;

__device__ __forceinline__ unsigned short f2bf(float f) {
  union { float f; unsigned u; } x; x.f = f;
  unsigned r = x.u + 0x7FFFu + ((x.u >> 16) & 1u);   // RNE
  return (unsigned short)(r >> 16);
}

// ---------------- mask -> bitmask (1 bit per element, 64 j's per u64) -------
__global__ void pack_mask_k(const int* __restrict__ mask, u64* __restrict__ bits,
                            int nwords) {
  int lane = threadIdx.x & 63;
  int w0 = (blockIdx.x * blockDim.x + threadIdx.x) >> 6;
  int stride = (gridDim.x * blockDim.x) >> 6;
  for (int w = w0; w < nwords; w += stride) {
    int m = mask[(size_t)w * 64 + lane];
    u64 b = __ballot(m != 0);
    if (lane == 0) bits[w] = b;
  }
}

// ---------------- GEMM: C[token, feat] = X @ W^T + bias ---------------------
// MODE 0: X fp32 (q/k/v via grid.z), W=wq fp32, out bf16 qp/kp [B,H,L,64], vpT [B,H,64,L]
// MODE 1: X bf16 ctx [B*L, 512], W=wo fp32, out fp32 d_out [B*L,512]
template<int MODE>
__global__ __launch_bounds__(256, 2)
void gemm_k(const void* __restrict__ A0, const void* __restrict__ A1,
            const void* __restrict__ A2, const float* __restrict__ Bw,
            const float* __restrict__ bias,
            void* __restrict__ O0, void* __restrict__ O1, void* __restrict__ O2) {
  __shared__ __align__(16) unsigned short As[128 * 64];
  __shared__ __align__(16) unsigned short Bs[128 * 64];
  const int tid = threadIdx.x;
  const int lane = tid & 63;
  const int wv = tid >> 6, wr = wv >> 1, wc = wv & 1;
  const int c = lane & 15, g = lane >> 4;
  const int m0 = blockIdx.x * 128, n0 = blockIdx.y * 128;
  const int z = blockIdx.z;
  const void* Ap = (z == 0) ? A0 : (z == 1) ? A1 : A2;
  void* Op = (z == 0) ? O0 : (z == 1) ? O1 : O2;

  f32x4 acc[4][4] = {};

  for (int kit = 0; kit < 8; ++kit) {
    const int k0 = kit * 64;
    if (kit) __syncthreads();
    // stage A
    if constexpr (MODE == 1) {
      const unsigned short* A = (const unsigned short*)Ap;
      #pragma unroll
      for (int f = 0; f < 4; ++f) {
        int p = tid + f * 256;
        int row = p >> 3, ch = p & 7;
        i32x4 vdat = *(const i32x4*)(A + (size_t)(m0 + row) * DM + k0 + ch * 8);
        *(i32x4*)(As + row * 64 + ((ch ^ (row & 7)) * 8)) = vdat;
      }
    } else {
      const float* A = (const float*)Ap;
      #pragma unroll
      for (int f = 0; f < 8; ++f) {
        int p = tid + f * 256;
        int row = p >> 4, c4 = p & 15;
        f32x4 vv = *(const f32x4*)(A + (size_t)(m0 + row) * DM + k0 + c4 * 4);
        u16x4 hh = { f2bf(vv[0]), f2bf(vv[1]), f2bf(vv[2]), f2bf(vv[3]) };
        int ch = c4 >> 1, half = c4 & 1;
        *(u16x4*)(As + row * 64 + ((ch ^ (row & 7)) * 8) + half * 4) = hh;
      }
    }
    // stage B (weights fp32, rows = output features, B^T pattern)
    #pragma unroll
    for (int f = 0; f < 8; ++f) {
      int p = tid + f * 256;
      int row = p >> 4, c4 = p & 15;
      f32x4 vv = *(const f32x4*)(Bw + (size_t)(n0 + row) * DM + k0 + c4 * 4);
      u16x4 hh = { f2bf(vv[0]), f2bf(vv[1]), f2bf(vv[2]), f2bf(vv[3]) };
      int ch = c4 >> 1, half = c4 & 1;
      *(u16x4*)(Bs + row * 64 + ((ch ^ (row & 7)) * 8) + half * 4) = hh;
    }
    __syncthreads();
    #pragma unroll
    for (int ks = 0; ks < 2; ++ks) {
      bf16x8 av[4], bv_[4];
      #pragma unroll
      for (int m = 0; m < 4; ++m) {
        int row = wr * 64 + m * 16 + c;
        av[m] = *(const bf16x8*)(As + row * 64 + (((ks * 4 + g) ^ (row & 7)) * 8));
      }
      #pragma unroll
      for (int n = 0; n < 4; ++n) {
        int row = wc * 64 + n * 16 + c;
        bv_[n] = *(const bf16x8*)(Bs + row * 64 + (((ks * 4 + g) ^ (row & 7)) * 8));
      }
      #pragma unroll
      for (int m = 0; m < 4; ++m)
        #pragma unroll
        for (int n = 0; n < 4; ++n)
          acc[m][n] = __builtin_amdgcn_mfma_f32_16x16x32_bf16(av[m], bv_[n], acc[m][n], 0, 0, 0);
    }
  }

  float bvx[4];
  #pragma unroll
  for (int n = 0; n < 4; ++n) bvx[n] = bias[n0 + wc * 64 + n * 16 + c];

  if constexpr (MODE == 0) {
    unsigned short* O = (unsigned short*)Op;
    if (z < 2) {
      // qp / kp : [B,H,L,64] bf16
      #pragma unroll
      for (int n = 0; n < 4; ++n) {
        int j = n0 + wc * 64 + n * 16 + c;
        int hd = j >> 6, d = j & 63;
        #pragma unroll
        for (int m = 0; m < 4; ++m) {
          int ib = m0 + wr * 64 + m * 16 + g * 4;
          int bb = ib >> 11, tok = ib & (L_SEQ - 1);
          size_t base = (((size_t)(bb * NH + hd)) * L_SEQ + tok) * DH + d;
          #pragma unroll
          for (int r = 0; r < 4; ++r)
            O[base + (size_t)r * DH] = f2bf(acc[m][n][r] + bvx[n]);
        }
      }
    } else {
      // vpT : [B,H,64,L] bf16, packed 4 tokens per store
      #pragma unroll
      for (int n = 0; n < 4; ++n) {
        int j = n0 + wc * 64 + n * 16 + c;
        int hd = j >> 6, d = j & 63;
        #pragma unroll
        for (int m = 0; m < 4; ++m) {
          int ib = m0 + wr * 64 + m * 16 + g * 4;
          int bb = ib >> 11, tok = ib & (L_SEQ - 1);
          u16x4 hh = { f2bf(acc[m][n][0] + bvx[n]), f2bf(acc[m][n][1] + bvx[n]),
                       f2bf(acc[m][n][2] + bvx[n]), f2bf(acc[m][n][3] + bvx[n]) };
          *(u16x4*)(O + (((size_t)(bb * NH + hd)) * DH + d) * L_SEQ + tok) = hh;
        }
      }
    }
  } else {
    float* O = (float*)Op;   // d_out [B*L, 512] fp32
    #pragma unroll
    for (int n = 0; n < 4; ++n) {
      int j = n0 + wc * 64 + n * 16 + c;
      #pragma unroll
      for (int m = 0; m < 4; ++m) {
        int ib = m0 + wr * 64 + m * 16 + g * 4;
        #pragma unroll
        for (int r = 0; r < 4; ++r)
          O[(size_t)(ib + r) * DM + j] = acc[m][n][r] + bvx[n];
      }
    }
  }
}

// ---------------- fused attention ------------------------------------------
// Computes S^T = mfma(K, Q) per tile (lane holds 4 consecutive j, fixed i).
// Sweep 1: row sums of masked exp (no max needed: |scores| <~ 2).
// Sweep 2: recompute S (bit-identical), write attn = exp/rowsum as float4,
//          stage E bf16 into swizzled LDS, PV mfma(vpT, E) -> ctx registers.
__global__ __launch_bounds__(256, 2)
void attn_k(const unsigned short* __restrict__ qp,
            const unsigned short* __restrict__ kp,
            const unsigned short* __restrict__ vpT,
            const u64* __restrict__ mbits,
            float* __restrict__ attn,
            unsigned short* __restrict__ ctx) {
  __shared__ __align__(16) unsigned short Elds[2][64][128];  // [wc][i][j] bf16
  __shared__ float rsl[2][128];
  const int tid = threadIdx.x;
  const int lane = tid & 63;
  const int wv = tid >> 6, wr = wv >> 1, wc = wv & 1;
  const int c = lane & 15, g = lane >> 4;
  const int bh = blockIdx.y, b = bh >> 3, hd = bh & 7;
  const int i0 = blockIdx.x * 128;
  const unsigned short* qb = qp + (size_t)bh * L_SEQ * DH;
  const unsigned short* kb = kp + (size_t)bh * L_SEQ * DH;
  const unsigned short* vb = vpT + (size_t)bh * DH * L_SEQ;
  float* ab = attn + (size_t)bh * L_SEQ * L_SEQ;
  const float SC = 0.044194173824159216f;  // 1/sqrt(512)

  // Q fragments in registers for the whole kernel (B-operand of S^T)
  bf16x8 qf[4][2];
  #pragma unroll
  for (int n = 0; n < 4; ++n)
    #pragma unroll
    for (int k = 0; k < 2; ++k)
      qf[n][k] = *(const bf16x8*)(qb + (size_t)(i0 + wc * 64 + n * 16 + c) * DH + k * 32 + g * 8);

  float rs[4] = {0.f, 0.f, 0.f, 0.f};

  // ---- sweep 1: row sums ----
  for (int j0 = 0; j0 < L_SEQ; j0 += 128) {
    f32x4 acc[4][4] = {};
    #pragma unroll
    for (int k = 0; k < 2; ++k) {
      bf16x8 kf[4];
      #pragma unroll
      for (int m = 0; m < 4; ++m)
        kf[m] = *(const bf16x8*)(kb + (size_t)(j0 + wr * 64 + m * 16 + c) * DH + k * 32 + g * 8);
      #pragma unroll
      for (int m = 0; m < 4; ++m)
        #pragma unroll
        for (int n = 0; n < 4; ++n)
          acc[m][n] = __builtin_amdgcn_mfma_f32_16x16x32_bf16(kf[m], qf[n][k], acc[m][n], 0, 0, 0);
    }
    #pragma unroll
    for (int n = 0; n < 4; ++n) {
      int i = i0 + wc * 64 + n * 16 + c;
      u64 w = mbits[((size_t)b * L_SEQ + i) * (L_SEQ / 64) + (j0 >> 6) + wr];
      #pragma unroll
      for (int m = 0; m < 4; ++m)
        #pragma unroll
        for (int r = 0; r < 4; ++r) {
          float e = ((w >> (m * 16 + g * 4 + r)) & 1) ? __expf(acc[m][n][r] * SC) : 0.0f;
          rs[n] += e;
        }
    }
  }
  // reduce over j-lanes (g) then across wr waves via LDS
  #pragma unroll
  for (int n = 0; n < 4; ++n) {
    rs[n] += __shfl_xor(rs[n], 16);
    rs[n] += __shfl_xor(rs[n], 32);
  }
  if (g == 0) {
    #pragma unroll
    for (int n = 0; n < 4; ++n) rsl[wr][wc * 64 + n * 16 + c] = rs[n];
  }
  __syncthreads();
  float inv[4];
  #pragma unroll
  for (int n = 0; n < 4; ++n) {
    int il = wc * 64 + n * 16 + c;
    inv[n] = 1.0f / (rsl[0][il] + rsl[1][il]);
  }

  f32x4 acc2[4][2] = {};          // ctx^T [d, i] per wave
  const int wcE = wv >> 1;
  const int ilb = 32 * (wv & 1);

  // ---- sweep 2: recompute, write attn, PV ----
  for (int j0 = 0; j0 < L_SEQ; j0 += 128) {
    f32x4 acc[4][4] = {};
    #pragma unroll
    for (int k = 0; k < 2; ++k) {
      bf16x8 kf[4];
      #pragma unroll
      for (int m = 0; m < 4; ++m)
        kf[m] = *(const bf16x8*)(kb + (size_t)(j0 + wr * 64 + m * 16 + c) * DH + k * 32 + g * 8);
      #pragma unroll
      for (int m = 0; m < 4; ++m)
        #pragma unroll
        for (int n = 0; n < 4; ++n)
          acc[m][n] = __builtin_amdgcn_mfma_f32_16x16x32_bf16(kf[m], qf[n][k], acc[m][n], 0, 0, 0);
    }
    #pragma unroll
    for (int n = 0; n < 4; ++n) {
      int i = i0 + wc * 64 + n * 16 + c;
      u64 w = mbits[((size_t)b * L_SEQ + i) * (L_SEQ / 64) + (j0 >> 6) + wr];
      int il = n * 16 + c;
      #pragma unroll
      for (int m = 0; m < 4; ++m) {
        f32x4 fe;
        u16x4 he;
        #pragma unroll
        for (int r = 0; r < 4; ++r) {
          float e = ((w >> (m * 16 + g * 4 + r)) & 1) ? __expf(acc[m][n][r] * SC) : 0.0f;
          float val = e * inv[n];
          fe[r] = val;
          he[r] = f2bf(val);
        }
        *(f32x4*)(ab + (size_t)i * L_SEQ + j0 + wr * 64 + m * 16 + g * 4) = fe;
        int byteoff = (wr * 64 + m * 16 + g * 4) * 2;
        int fin = (byteoff & 15) | (((byteoff >> 4) ^ (il & 7)) << 4);
        *(u16x4*)((char*)(&Elds[wc][il][0]) + fin) = he;
      }
    }
    __syncthreads();
    // PV: C'[d, i] += vpT[d, j] * E[i, j]
    #pragma unroll
    for (int ks = 0; ks < 4; ++ks) {
      bf16x8 ef[2];
      #pragma unroll
      for (int np = 0; np < 2; ++np) {
        int il = ilb + np * 16 + c;
        int fin = (((4 * ks + g) ^ (il & 7)) << 4);
        ef[np] = *(const bf16x8*)((const char*)(&Elds[wcE][il][0]) + fin);
      }
      bf16x8 vf[4];
      #pragma unroll
      for (int mp = 0; mp < 4; ++mp)
        vf[mp] = *(const bf16x8*)(vb + (size_t)(mp * 16 + c) * L_SEQ + j0 + ks * 32 + g * 8);
      #pragma unroll
      for (int mp = 0; mp < 4; ++mp)
        #pragma unroll
        for (int np = 0; np < 2; ++np)
          acc2[mp][np] = __builtin_amdgcn_mfma_f32_16x16x32_bf16(vf[mp], ef[np], acc2[mp][np], 0, 0, 0);
    }
    __syncthreads();
  }
  // write ctx bf16 [B*L, 512]; lane holds 4 consecutive d for fixed i
  #pragma unroll
  for (int np = 0; np < 2; ++np) {
    int i = i0 + 32 * wv + np * 16 + c;
    size_t base = ((size_t)b * L_SEQ + i) * DM + hd * 64;
    #pragma unroll
    for (int mp = 0; mp < 4; ++mp) {
      u16x4 hh = { f2bf(acc2[mp][np][0]), f2bf(acc2[mp][np][1]),
                   f2bf(acc2[mp][np][2]), f2bf(acc2[mp][np][3]) };
      *(u16x4*)(ctx + base + mp * 16 + g * 4) = hh;
    }
  }
}

// ---------------- launch ----------------------------------------------------
extern "C" void kernel_launch(void* const* d_in, const int* in_sizes, int n_in,
                              void* d_out, int out_size, void* d_ws, size_t ws_size,
                              hipStream_t stream) {
  const float* q    = (const float*)d_in[0];
  const float* k    = (const float*)d_in[1];
  const float* v    = (const float*)d_in[2];
  const int*   mask = (const int*)d_in[3];
  const float* wq   = (const float*)d_in[4];
  const float* bq   = (const float*)d_in[5];
  const float* wo   = (const float*)d_in[6];
  const float* bo   = (const float*)d_in[7];

  float* out  = (float*)d_out;
  float* attn = out + (size_t)NB * L_SEQ * DM;

  const size_t HEAD_ELEMS = (size_t)NB * NH * L_SEQ * DH;   // 4,194,304
  unsigned short* qp  = (unsigned short*)d_ws;
  unsigned short* kpb = qp + HEAD_ELEMS;
  unsigned short* vpT = kpb + HEAD_ELEMS;
  unsigned short* ctx = vpT + HEAD_ELEMS;
  u64* mbits = (u64*)(ctx + (size_t)NB * L_SEQ * DM);

  pack_mask_k<<<2048, 256, 0, stream>>>(mask, mbits, NB * L_SEQ * (L_SEQ / 64));

  dim3 gproj(64, 4, 3);
  gemm_k<0><<<gproj, 256, 0, stream>>>(q, k, v, wq, bq, qp, kpb, vpT);

  attn_k<<<dim3(L_SEQ / 128, NB * NH), 256, 0, stream>>>(qp, kpb, vpT, mbits, attn, ctx);

  dim3 gout(64, 4, 1);
  gemm_k<1><<<gout, 256, 0, stream>>>(ctx, nullptr, nullptr, wo, bo, out, nullptr, nullptr);
}

// Round 2
// 328.594 us; speedup vs baseline: 1.2465x; 1.2465x over previous
//
#include <hip/hip_runtime.h>
#include <hip/hip_bf16.h>

#define L_SEQ 2048
#define DM 512
#define NH 8
#define DH 64
#define NB 4

typedef __attribute__((ext_vector_type(4))) float f32x4;
typedef __attribute__((ext_vector_type(8))) short bf16x8;
typedef __attribute__((ext_vector_type(4))) unsigned short u16x4;
typedef __attribute__((ext_vector_type(4))) int i32x4;
typedef unsigned long long u64;

__device__ __forceinline__ unsigned short f2bf(float f) {
  __hip_bfloat16 h = __float2bfloat16(f);
  union { __hip_bfloat16 h; unsigned short u; } cv; cv.h = h; return cv.u;
}

__device__ __forceinline__ float fexp2(float x) {
#if __has_builtin(__builtin_amdgcn_exp2f)
  return __builtin_amdgcn_exp2f(x);
#else
  return __expf(x * 0.6931471805599453f);
#endif
}

// ---------------- mask -> bitmask (1 bit per element, 64 j's per u64) -------
__global__ void pack_mask_k(const int* __restrict__ mask, u64* __restrict__ bits,
                            int nwords) {
  int lane = threadIdx.x & 63;
  int w0 = (blockIdx.x * blockDim.x + threadIdx.x) >> 6;
  int stride = (gridDim.x * blockDim.x) >> 6;
  for (int w = w0; w < nwords; w += stride) {
    int m = mask[(size_t)w * 64 + lane];
    u64 b = __ballot(m != 0);
    if (lane == 0) bits[w] = b;
  }
}

// ---------------- GEMM: C[token, feat] = X @ W^T + bias ---------------------
// MODE 0: X fp32 (q/k/v via grid.z), W=wq fp32, out bf16 qp/kp [B,H,L,64], vpT [B,H,64,L]
// MODE 1: X bf16 ctx [B*L, 512], W=wo fp32, out fp32 d_out [B*L,512]
template<int MODE>
__global__ __launch_bounds__(256, 2)
void gemm_k(const void* __restrict__ A0, const void* __restrict__ A1,
            const void* __restrict__ A2, const float* __restrict__ Bw,
            const float* __restrict__ bias,
            void* __restrict__ O0, void* __restrict__ O1, void* __restrict__ O2) {
  __shared__ __align__(16) unsigned short As[128 * 64];
  __shared__ __align__(16) unsigned short Bs[128 * 64];
  const int tid = threadIdx.x;
  const int lane = tid & 63;
  const int wv = tid >> 6, wr = wv >> 1, wc = wv & 1;
  const int c = lane & 15, g = lane >> 4;
  const int m0 = blockIdx.x * 128, n0 = blockIdx.y * 128;
  const int z = blockIdx.z;
  const void* Ap = (z == 0) ? A0 : (z == 1) ? A1 : A2;
  void* Op = (z == 0) ? O0 : (z == 1) ? O1 : O2;

  f32x4 acc[4][4] = {};

  for (int kit = 0; kit < 8; ++kit) {
    const int k0 = kit * 64;
    if (kit) __syncthreads();
    // stage A
    if constexpr (MODE == 1) {
      const unsigned short* A = (const unsigned short*)Ap;
      #pragma unroll
      for (int f = 0; f < 4; ++f) {
        int p = tid + f * 256;
        int row = p >> 3, ch = p & 7;
        i32x4 vdat = *(const i32x4*)(A + (size_t)(m0 + row) * DM + k0 + ch * 8);
        *(i32x4*)(As + row * 64 + ((ch ^ (row & 7)) * 8)) = vdat;
      }
    } else {
      const float* A = (const float*)Ap;
      #pragma unroll
      for (int f = 0; f < 8; ++f) {
        int p = tid + f * 256;
        int row = p >> 4, c4 = p & 15;
        f32x4 vv = *(const f32x4*)(A + (size_t)(m0 + row) * DM + k0 + c4 * 4);
        u16x4 hh = { f2bf(vv[0]), f2bf(vv[1]), f2bf(vv[2]), f2bf(vv[3]) };
        int ch = c4 >> 1, half = c4 & 1;
        *(u16x4*)(As + row * 64 + ((ch ^ (row & 7)) * 8) + half * 4) = hh;
      }
    }
    // stage B (weights fp32, rows = output features, B^T pattern)
    #pragma unroll
    for (int f = 0; f < 8; ++f) {
      int p = tid + f * 256;
      int row = p >> 4, c4 = p & 15;
      f32x4 vv = *(const f32x4*)(Bw + (size_t)(n0 + row) * DM + k0 + c4 * 4);
      u16x4 hh = { f2bf(vv[0]), f2bf(vv[1]), f2bf(vv[2]), f2bf(vv[3]) };
      int ch = c4 >> 1, half = c4 & 1;
      *(u16x4*)(Bs + row * 64 + ((ch ^ (row & 7)) * 8) + half * 4) = hh;
    }
    __syncthreads();
    #pragma unroll
    for (int ks = 0; ks < 2; ++ks) {
      bf16x8 av[4], bv_[4];
      #pragma unroll
      for (int m = 0; m < 4; ++m) {
        int row = wr * 64 + m * 16 + c;
        av[m] = *(const bf16x8*)(As + row * 64 + (((ks * 4 + g) ^ (row & 7)) * 8));
      }
      #pragma unroll
      for (int n = 0; n < 4; ++n) {
        int row = wc * 64 + n * 16 + c;
        bv_[n] = *(const bf16x8*)(Bs + row * 64 + (((ks * 4 + g) ^ (row & 7)) * 8));
      }
      __builtin_amdgcn_s_setprio(1);
      #pragma unroll
      for (int m = 0; m < 4; ++m)
        #pragma unroll
        for (int n = 0; n < 4; ++n)
          acc[m][n] = __builtin_amdgcn_mfma_f32_16x16x32_bf16(av[m], bv_[n], acc[m][n], 0, 0, 0);
      __builtin_amdgcn_s_setprio(0);
    }
  }

  float bvx[4];
  #pragma unroll
  for (int n = 0; n < 4; ++n) bvx[n] = bias[n0 + wc * 64 + n * 16 + c];

  if constexpr (MODE == 0) {
    unsigned short* O = (unsigned short*)Op;
    if (z < 2) {
      // qp / kp : [B,H,L,64] bf16
      #pragma unroll
      for (int n = 0; n < 4; ++n) {
        int j = n0 + wc * 64 + n * 16 + c;
        int hd = j >> 6, d = j & 63;
        #pragma unroll
        for (int m = 0; m < 4; ++m) {
          int ib = m0 + wr * 64 + m * 16 + g * 4;
          int bb = ib >> 11, tok = ib & (L_SEQ - 1);
          size_t base = (((size_t)(bb * NH + hd)) * L_SEQ + tok) * DH + d;
          #pragma unroll
          for (int r = 0; r < 4; ++r)
            O[base + (size_t)r * DH] = f2bf(acc[m][n][r] + bvx[n]);
        }
      }
    } else {
      // vpT : [B,H,64,L] bf16, packed 4 tokens per store
      #pragma unroll
      for (int n = 0; n < 4; ++n) {
        int j = n0 + wc * 64 + n * 16 + c;
        int hd = j >> 6, d = j & 63;
        #pragma unroll
        for (int m = 0; m < 4; ++m) {
          int ib = m0 + wr * 64 + m * 16 + g * 4;
          int bb = ib >> 11, tok = ib & (L_SEQ - 1);
          u16x4 hh = { f2bf(acc[m][n][0] + bvx[n]), f2bf(acc[m][n][1] + bvx[n]),
                       f2bf(acc[m][n][2] + bvx[n]), f2bf(acc[m][n][3] + bvx[n]) };
          *(u16x4*)(O + (((size_t)(bb * NH + hd)) * DH + d) * L_SEQ + tok) = hh;
        }
      }
    }
  } else {
    float* O = (float*)Op;   // d_out [B*L, 512] fp32
    #pragma unroll
    for (int n = 0; n < 4; ++n) {
      int j = n0 + wc * 64 + n * 16 + c;
      #pragma unroll
      for (int m = 0; m < 4; ++m) {
        int ib = m0 + wr * 64 + m * 16 + g * 4;
        #pragma unroll
        for (int r = 0; r < 4; ++r)
          O[(size_t)(ib + r) * DM + j] = acc[m][n][r] + bvx[n];
      }
    }
  }
}

// ---------------- fused attention ------------------------------------------
// S^T = mfma(K, Q); sweep 1: row sums of masked exp2; sweep 2: recompute,
// write normalized attn (normalization folded into exponent), PV via
// double-buffered swizzled LDS with ONE raw s_barrier per tile (no vmcnt
// drain -> attn stores stream freely).
__global__ __launch_bounds__(256, 2)
void attn_k(const unsigned short* __restrict__ qp,
            const unsigned short* __restrict__ kp,
            const unsigned short* __restrict__ vpT,
            const u64* __restrict__ mbits,
            float* __restrict__ attn,
            unsigned short* __restrict__ ctx) {
  __shared__ __align__(16) unsigned short Elds[2][2][64][128];  // [buf][wc][i][j]
  __shared__ float rsl[2][128];
  const int tid = threadIdx.x;
  const int lane = tid & 63;
  const int wv = tid >> 6, wr = wv >> 1, wc = wv & 1;
  const int c = lane & 15, g = lane >> 4;
  // XCD-aware swizzle: 512 blocks -> 64 consecutive works per XCD (4 heads/XCD)
  const int slot = blockIdx.x + blockIdx.y * gridDim.x;
  const int work = (slot & 7) * 64 + (slot >> 3);
  const int bh = work >> 4;
  const int i0 = (work & 15) * 128;
  const int b = bh >> 3;
  const unsigned short* qb = qp + (size_t)bh * L_SEQ * DH;
  const unsigned short* kb = kp + (size_t)bh * L_SEQ * DH;
  const unsigned short* vb = vpT + (size_t)bh * DH * L_SEQ;
  float* ab = attn + (size_t)bh * L_SEQ * L_SEQ;
  const float SCL2 = 0.044194173824159216f * 1.4426950408889634f;  // 1/sqrt(512)*log2(e)
  const float NINF = -__builtin_inff();

  // Q fragments in registers for the whole kernel (B-operand of S^T)
  bf16x8 qf[4][2];
  #pragma unroll
  for (int n = 0; n < 4; ++n)
    #pragma unroll
    for (int k = 0; k < 2; ++k)
      qf[n][k] = *(const bf16x8*)(qb + (size_t)(i0 + wc * 64 + n * 16 + c) * DH + k * 32 + g * 8);

  float rs[4] = {0.f, 0.f, 0.f, 0.f};

  // ---- sweep 1: row sums ----
  for (int j0 = 0; j0 < L_SEQ; j0 += 128) {
    f32x4 acc[4][4] = {};
    #pragma unroll
    for (int k = 0; k < 2; ++k) {
      bf16x8 kf[4];
      #pragma unroll
      for (int m = 0; m < 4; ++m)
        kf[m] = *(const bf16x8*)(kb + (size_t)(j0 + wr * 64 + m * 16 + c) * DH + k * 32 + g * 8);
      __builtin_amdgcn_s_setprio(1);
      #pragma unroll
      for (int m = 0; m < 4; ++m)
        #pragma unroll
        for (int n = 0; n < 4; ++n)
          acc[m][n] = __builtin_amdgcn_mfma_f32_16x16x32_bf16(kf[m], qf[n][k], acc[m][n], 0, 0, 0);
      __builtin_amdgcn_s_setprio(0);
    }
    #pragma unroll
    for (int n = 0; n < 4; ++n) {
      int i = i0 + wc * 64 + n * 16 + c;
      u64 w = mbits[((size_t)b * L_SEQ + i) * (L_SEQ / 64) + (j0 >> 6) + wr];
      #pragma unroll
      for (int m = 0; m < 4; ++m) {
        unsigned mw = (unsigned)(w >> (m * 16 + g * 4)) & 0xFu;
        #pragma unroll
        for (int r = 0; r < 4; ++r) {
          float arg = ((mw >> r) & 1) ? acc[m][n][r] * SCL2 : NINF;
          rs[n] += fexp2(arg);
        }
      }
    }
  }
  // reduce over j-lanes (g) then across wr waves via LDS
  #pragma unroll
  for (int n = 0; n < 4; ++n) {
    rs[n] += __shfl_xor(rs[n], 16);
    rs[n] += __shfl_xor(rs[n], 32);
  }
  if (g == 0) {
    #pragma unroll
    for (int n = 0; n < 4; ++n) rsl[wr][wc * 64 + n * 16 + c] = rs[n];
  }
  __syncthreads();
  float l2i[4];
  #pragma unroll
  for (int n = 0; n < 4; ++n) {
    int il = wc * 64 + n * 16 + c;
    l2i[n] = -__log2f(rsl[0][il] + rsl[1][il]);
  }

  f32x4 acc2[4][2] = {};          // ctx^T [d, i] per wave
  const int wcE = wv >> 1;
  const int ilb = 32 * (wv & 1);

  // ---- sweep 2: recompute, write attn, PV (1 raw barrier/tile, dbuf LDS) ----
  for (int j0b = 0; j0b < L_SEQ; j0b += 256) {
    #pragma unroll
    for (int half = 0; half < 2; ++half) {
      const int j0 = j0b + half * 128;
      // S^T
      f32x4 acc[4][4] = {};
      #pragma unroll
      for (int k = 0; k < 2; ++k) {
        bf16x8 kf[4];
        #pragma unroll
        for (int m = 0; m < 4; ++m)
          kf[m] = *(const bf16x8*)(kb + (size_t)(j0 + wr * 64 + m * 16 + c) * DH + k * 32 + g * 8);
        __builtin_amdgcn_s_setprio(1);
        #pragma unroll
        for (int m = 0; m < 4; ++m)
          #pragma unroll
          for (int n = 0; n < 4; ++n)
            acc[m][n] = __builtin_amdgcn_mfma_f32_16x16x32_bf16(kf[m], qf[n][k], acc[m][n], 0, 0, 0);
        __builtin_amdgcn_s_setprio(0);
      }
      // preload PV operands (first half) + mask words BEFORE issuing stores,
      // so later vmcnt waits never have to drain the attn stores.
      bf16x8 vf01[2][4];
      #pragma unroll
      for (int ks = 0; ks < 2; ++ks)
        #pragma unroll
        for (int mp = 0; mp < 4; ++mp)
          vf01[ks][mp] = *(const bf16x8*)(vb + (size_t)(mp * 16 + c) * L_SEQ + j0 + ks * 32 + g * 8);
      u64 wm[4];
      #pragma unroll
      for (int n = 0; n < 4; ++n)
        wm[n] = mbits[((size_t)b * L_SEQ + (i0 + wc * 64 + n * 16 + c)) * (L_SEQ / 64) + (j0 >> 6) + wr];
      __builtin_amdgcn_sched_barrier(0);
      // E phase: normalized exp, nontemporal attn store, swizzled LDS stage
      #pragma unroll
      for (int n = 0; n < 4; ++n) {
        int i = i0 + wc * 64 + n * 16 + c;
        int il = n * 16 + c;
        #pragma unroll
        for (int m = 0; m < 4; ++m) {
          unsigned mw = (unsigned)(wm[n] >> (m * 16 + g * 4)) & 0xFu;
          f32x4 fe;
          u16x4 he;
          #pragma unroll
          for (int r = 0; r < 4; ++r) {
            float arg = ((mw >> r) & 1) ? fmaf(acc[m][n][r], SCL2, l2i[n]) : NINF;
            float val = fexp2(arg);
            fe[r] = val;
            he[r] = f2bf(val);
          }
          __builtin_nontemporal_store(fe, (f32x4*)(ab + (size_t)i * L_SEQ + j0 + wr * 64 + m * 16 + g * 4));
          int byteoff = (wr * 64 + m * 16 + g * 4) * 2;
          int fin = (byteoff & 15) | (((byteoff >> 4) ^ (il & 7)) << 4);
          *(u16x4*)((char*)(&Elds[half][wc][il][0]) + fin) = he;
        }
      }
      asm volatile("s_waitcnt lgkmcnt(0)" ::: "memory");
      __builtin_amdgcn_sched_barrier(0);
      __builtin_amdgcn_s_barrier();
      __builtin_amdgcn_sched_barrier(0);
      // second half of V fragments (ages during first PV half)
      bf16x8 vf23[2][4];
      #pragma unroll
      for (int ks = 0; ks < 2; ++ks)
        #pragma unroll
        for (int mp = 0; mp < 4; ++mp)
          vf23[ks][mp] = *(const bf16x8*)(vb + (size_t)(mp * 16 + c) * L_SEQ + j0 + (ks + 2) * 32 + g * 8);
      // PV: C'[d, i] += vpT[d, j] * E[i, j]
      __builtin_amdgcn_s_setprio(1);
      #pragma unroll
      for (int ks = 0; ks < 4; ++ks) {
        bf16x8 ef[2];
        #pragma unroll
        for (int np = 0; np < 2; ++np) {
          int il = ilb + np * 16 + c;
          int fin = (((4 * ks + g) ^ (il & 7)) << 4);
          ef[np] = *(const bf16x8*)((const char*)(&Elds[half][wcE][il][0]) + fin);
        }
        #pragma unroll
        for (int mp = 0; mp < 4; ++mp) {
          bf16x8 vfm = (ks < 2) ? vf01[ks][mp] : vf23[ks - 2][mp];
          #pragma unroll
          for (int np = 0; np < 2; ++np)
            acc2[mp][np] = __builtin_amdgcn_mfma_f32_16x16x32_bf16(vfm, ef[np], acc2[mp][np], 0, 0, 0);
        }
      }
      __builtin_amdgcn_s_setprio(0);
    }
  }
  // write ctx bf16 [B*L, 512]; lane holds 4 consecutive d for fixed i
  const int hd = bh & 7;
  #pragma unroll
  for (int np = 0; np < 2; ++np) {
    int i = i0 + 32 * wv + np * 16 + c;
    size_t base = ((size_t)b * L_SEQ + i) * DM + hd * 64;
    #pragma unroll
    for (int mp = 0; mp < 4; ++mp) {
      u16x4 hh = { f2bf(acc2[mp][np][0]), f2bf(acc2[mp][np][1]),
                   f2bf(acc2[mp][np][2]), f2bf(acc2[mp][np][3]) };
      *(u16x4*)(ctx + base + mp * 16 + g * 4) = hh;
    }
  }
}

// ---------------- launch ----------------------------------------------------
extern "C" void kernel_launch(void* const* d_in, const int* in_sizes, int n_in,
                              void* d_out, int out_size, void* d_ws, size_t ws_size,
                              hipStream_t stream) {
  const float* q    = (const float*)d_in[0];
  const float* k    = (const float*)d_in[1];
  const float* v    = (const float*)d_in[2];
  const int*   mask = (const int*)d_in[3];
  const float* wq   = (const float*)d_in[4];
  const float* bq   = (const float*)d_in[5];
  const float* wo   = (const float*)d_in[6];
  const float* bo   = (const float*)d_in[7];

  float* out  = (float*)d_out;
  float* attn = out + (size_t)NB * L_SEQ * DM;

  const size_t HEAD_ELEMS = (size_t)NB * NH * L_SEQ * DH;   // 4,194,304
  unsigned short* qp  = (unsigned short*)d_ws;
  unsigned short* kpb = qp + HEAD_ELEMS;
  unsigned short* vpT = kpb + HEAD_ELEMS;
  unsigned short* ctx = vpT + HEAD_ELEMS;
  u64* mbits = (u64*)(ctx + (size_t)NB * L_SEQ * DM);

  pack_mask_k<<<2048, 256, 0, stream>>>(mask, mbits, NB * L_SEQ * (L_SEQ / 64));

  dim3 gproj(64, 4, 3);
  gemm_k<0><<<gproj, 256, 0, stream>>>(q, k, v, wq, bq, qp, kpb, vpT);

  attn_k<<<dim3(L_SEQ / 128, NB * NH), 256, 0, stream>>>(qp, kpb, vpT, mbits, attn, ctx);

  dim3 gout(64, 4, 1);
  gemm_k<1><<<gout, 256, 0, stream>>>(ctx, nullptr, nullptr, wo, bo, out, nullptr, nullptr);
}